// Round 4
// baseline (2376.174 us; speedup 1.0000x reference)
//
#include <hip/hip_runtime.h>
#include <math.h>

#define NB    512
#define FDIM  80
#define LEN   111
#define TDEC  222
#define CFDIM 32

__global__ __launch_bounds__(128, 1)
void attn_rnn_kernel(const float* __restrict__ g_in,
                     const float* __restrict__ enc_Wx, const float* __restrict__ enc_Wh, const float* __restrict__ enc_b,
                     const float* __restrict__ att_Wq, const float* __restrict__ att_bq,
                     const float* __restrict__ att_Wm, const float* __restrict__ att_bm,
                     const float* __restrict__ att_V,  const float* __restrict__ att_bv,
                     const float* __restrict__ loc_Wc, const float* __restrict__ loc_Wd,
                     const float* __restrict__ dec_Wx, const float* __restrict__ dec_Wh, const float* __restrict__ dec_b,
                     const float* __restrict__ out_W,  const float* __restrict__ out_b,
                     float* __restrict__ g_out)
{
  // All recurrence-visible state in DOUBLE (match float64 numpy reference);
  // raw weights stay fp32 (exact input values), promoted at use.
  __shared__ double eo[LEN*21];     // encoder h sequence  [111][20] pad 21
  __shared__ double mp[LEN*11];     // mem_proj            [111][10] pad 11
  __shared__ double attn_s[LEN];    // attention (doubles as prev_attn)
  __shared__ double z_s[80], h_s[20], c_s[20], q_s[10], ctx_s[20], pctx[120], red[4];
  __shared__ double wloc_s[10];
  __shared__ float  x_s[FDIM];
  __shared__ float  Wm_s[200], V_s[10], bq_s[10], bm_s[10], outW_s[20];

  const int tid  = threadIdx.x;
  const int b    = blockIdx.x;
  const int lane = tid & 63;
  const int wid  = tid >> 6;
  const float* inp = g_in + (size_t)b * LEN * FDIM;

  // ---- stage small weights ----
  // BUG FIX (root cause of rounds 0-3): att_Wm has 200 elements but the block
  // has 128 threads — the old `if (tid < 200)` guard left Wm_s[128..199]
  // uninitialized. Strided loop covers all 200.
  for (int k = tid; k < 200; k += 128) Wm_s[k] = att_Wm[k];
  if (tid < 10){
    V_s[tid]  = att_V[tid];
    bq_s[tid] = att_bq[tid];
    bm_s[tid] = att_bm[tid];
    double acc = 0.0;                        // wloc = loc_Wconv @ loc_Wd (k=1 conv collapses)
    for (int cf=0; cf<CFDIM; ++cf) acc += (double)loc_Wc[cf] * (double)loc_Wd[cf*10 + tid];
    wloc_s[tid] = acc;
  }
  if (tid < 20){ outW_s[tid] = out_W[tid]; h_s[tid] = 0.0; c_s[tid] = 0.0; }
  if (tid < LEN) attn_s[tid] = 0.0;
  const double bv = (double)att_bv[0];
  const double ob = (double)out_b[0];

  // ---- per-thread fp32 weight columns (static-index unrolled) ----
  float wx[80], wh[20], dwx[20], dwh[20];
  float eb = 0.f, db = 0.f;
  if (tid < 80){
    #pragma unroll
    for (int i=0;i<80;i++) wx[i] = enc_Wx[i*80 + tid];
    #pragma unroll
    for (int u=0;u<20;u++){ wh[u] = enc_Wh[u*80 + tid]; dwx[u] = dec_Wx[u*80 + tid]; dwh[u] = dec_Wh[u*80 + tid]; }
    eb = enc_b[tid]; db = dec_b[tid];
  }
  float wq[20];
  if (tid < 10){
    #pragma unroll
    for (int u=0;u<20;u++) wq[u] = att_Wq[u*10 + tid];
  }
  __syncthreads();

  // ================= encoder =================
  for (int t=0;t<LEN;t++){
    if (tid < 80) x_s[tid] = inp[t*FDIM + tid];
    __syncthreads();
    if (tid < 80){
      double acc = (double)eb;
      #pragma unroll
      for (int i=0;i<80;i++) acc += (double)x_s[i] * (double)wx[i];
      #pragma unroll
      for (int u=0;u<20;u++) acc += h_s[u] * (double)wh[u];
      z_s[tid] = acc;
    }
    __syncthreads();
    if (tid < 20){
      double zi=z_s[tid], zf=z_s[tid+20], zg=z_s[tid+40], zo=z_s[tid+60];
      double c = (1.0/(1.0+exp(-zf)))*c_s[tid] + (1.0/(1.0+exp(-zi)))*tanh(zg);
      double h = (1.0/(1.0+exp(-zo)))*tanh(c);
      c_s[tid] = c; h_s[tid] = h; eo[t*21 + tid] = h;
    }
    __syncthreads();
  }

  // ---- mem_proj = enc_out @ att_Wm + att_bm ----
  if (tid < LEN){
    for (int a=0;a<10;a++){
      double acc = (double)bm_s[a];
      #pragma unroll
      for (int u=0;u<20;u++) acc += eo[tid*21 + u] * (double)Wm_s[u*10 + a];
      mp[tid*11 + a] = acc;
    }
  }
  if (tid < 20){ h_s[tid] = 0.0; c_s[tid] = 0.0; }   // decoder state restarts at zero
  __syncthreads();

  // ================= decoder =================
  for (int t=0;t<TDEC;t++){
    // q = c @ att_Wq + bq   (query from CELL state, per reference)
    if (tid < 10){
      double acc = (double)bq_s[tid];
      #pragma unroll
      for (int u=0;u<20;u++) acc += c_s[u] * (double)wq[u];
      q_s[tid] = acc;
    }
    __syncthreads();

    // scores: sc[l] = sum_a tanh( mp[l][a] + q[a] + tanh(aprev[l]*wloc[a]) ) * V[a] + bv
    double sc = -1.0e300;
    if (tid < LEN){
      double ap  = attn_s[tid];
      double acc = bv;
      for (int a=0;a<10;a++){
        double pre = mp[tid*11 + a] + q_s[a] + tanh(wloc_s[a]*ap);
        acc += tanh(pre) * (double)V_s[a];
      }
      sc = acc;
    }
    // softmax over l
    double mx = sc;
    #pragma unroll
    for (int off=32; off>=1; off>>=1) mx = fmax(mx, __shfl_xor(mx, off, 64));
    if (lane == 0) red[wid] = mx;
    __syncthreads();
    mx = fmax(red[0], red[1]);
    double e = (tid < LEN) ? exp(sc - mx) : 0.0;
    double s = e;
    #pragma unroll
    for (int off=32; off>=1; off>>=1) s += __shfl_xor(s, off, 64);
    if (lane == 0) red[2+wid] = s;
    __syncthreads();
    double inv = 1.0 / (red[2] + red[3]);
    if (tid < LEN) attn_s[tid] = e * inv;
    __syncthreads();

    // ctx[u] = sum_l attn[l] * eo[l][u]  (6 groups over l, simple strided loops)
    if (tid < 120){
      int g = tid/20, u = tid%20;
      double p = 0.0;
      for (int l=g; l<LEN; l+=6) p += attn_s[l] * eo[l*21 + u];
      pctx[tid] = p;
    }
    __syncthreads();
    if (tid < 20){
      ctx_s[tid] = ((pctx[tid] + pctx[tid+20]) + (pctx[tid+40] + pctx[tid+60]))
                 + (pctx[tid+80] + pctx[tid+100]);
    }
    __syncthreads();

    // z = ctx @ dec_Wx + h @ dec_Wh + dec_b
    if (tid < 80){
      double acc = (double)db;
      #pragma unroll
      for (int u=0;u<20;u++) acc += ctx_s[u]*(double)dwx[u] + h_s[u]*(double)dwh[u];
      z_s[tid] = acc;
    }
    __syncthreads();

    // gates
    if (tid < 20){
      double zi=z_s[tid], zf=z_s[tid+20], zg=z_s[tid+40], zo=z_s[tid+60];
      double c = (1.0/(1.0+exp(-zf)))*c_s[tid] + (1.0/(1.0+exp(-zi)))*tanh(zg);
      double h = (1.0/(1.0+exp(-zo)))*tanh(c);
      c_s[tid] = c; h_s[tid] = h;
    }
    __syncthreads();

    // y = tanh(h @ out_W + out_b)  (thread 0, trivially serial)
    if (tid == 0){
      double acc = ob;
      #pragma unroll
      for (int u=0;u<20;u++) acc += h_s[u] * (double)outW_s[u];
      g_out[(size_t)b*TDEC + t] = (float)tanh(acc);
    }
    __syncthreads();
  }
}

extern "C" void kernel_launch(void* const* d_in, const int* in_sizes, int n_in,
                              void* d_out, int out_size, void* d_ws, size_t ws_size,
                              hipStream_t stream) {
  const float* g_in   = (const float*)d_in[0];
  const float* enc_Wx = (const float*)d_in[1];
  const float* enc_Wh = (const float*)d_in[2];
  const float* enc_b  = (const float*)d_in[3];
  const float* att_Wq = (const float*)d_in[4];
  const float* att_bq = (const float*)d_in[5];
  const float* att_Wm = (const float*)d_in[6];
  const float* att_bm = (const float*)d_in[7];
  const float* att_V  = (const float*)d_in[8];
  const float* att_bv = (const float*)d_in[9];
  const float* loc_Wc = (const float*)d_in[10];
  const float* loc_Wd = (const float*)d_in[11];
  const float* dec_Wx = (const float*)d_in[12];
  const float* dec_Wh = (const float*)d_in[13];
  const float* dec_b  = (const float*)d_in[14];
  const float* out_W  = (const float*)d_in[15];
  const float* out_b  = (const float*)d_in[16];
  float* g_out = (float*)d_out;

  hipLaunchKernelGGL(attn_rnn_kernel, dim3(NB), dim3(128), 0, stream,
                     g_in, enc_Wx, enc_Wh, enc_b, att_Wq, att_bq, att_Wm, att_bm,
                     att_V, att_bv, loc_Wc, loc_Wd, dec_Wx, dec_Wh, dec_b,
                     out_W, out_b, g_out);
}

// Round 5
// 803.634 us; speedup vs baseline: 2.9568x; 2.9568x over previous
//
#include <hip/hip_runtime.h>
#include <math.h>

#define NB    512
#define FDIM  80
#define LEN   111
#define TDEC  222
#define CFDIM 32

__device__ __forceinline__ float sigm(float x){
  return 1.0f / (1.0f + __expf(-x));
}
__device__ __forceinline__ float ftanh(float x){
  float ax = fabsf(x);
  float e  = __expf(-2.0f*ax);
  float r  = (1.0f - e) / (1.0f + e);
  return copysignf(r, x);
}

__global__ __launch_bounds__(128, 1)
void attn_rnn_kernel(const float* __restrict__ g_in,
                     const float* __restrict__ enc_Wx, const float* __restrict__ enc_Wh, const float* __restrict__ enc_b,
                     const float* __restrict__ att_Wq, const float* __restrict__ att_bq,
                     const float* __restrict__ att_Wm, const float* __restrict__ att_bm,
                     const float* __restrict__ att_V,  const float* __restrict__ att_bv,
                     const float* __restrict__ loc_Wc, const float* __restrict__ loc_Wd,
                     const float* __restrict__ dec_Wx, const float* __restrict__ dec_Wh, const float* __restrict__ dec_b,
                     const float* __restrict__ out_W,  const float* __restrict__ out_b,
                     float* __restrict__ g_out)
{
  __shared__ float eo[LEN*21];     // encoder h sequence  [111][20] pad 21
  __shared__ float mp[LEN*11];     // mem_proj            [111][10] pad 11
  __shared__ float attn_s[LEN];    // attention (doubles as prev_attn)
  __shared__ float z_s[80], h_s[20], c_s[20], q_s[10], ctx_s[20], pctx[120], red[4];
  __shared__ float wloc_s[10];
  __shared__ float x_s[FDIM];
  __shared__ float Wm_s[200], V_s[10], bq_s[10], bm_s[10], outW_s[20];

  const int tid  = threadIdx.x;
  const int b    = blockIdx.x;
  const int lane = tid & 63;
  const int wid  = tid >> 6;
  const float* inp = g_in + (size_t)b * LEN * FDIM;

  // ---- stage small weights ----
  // (128-thread block: strided loop, NOT `if (tid<200)` — that was the r0-r3 bug)
  for (int k = tid; k < 200; k += 128) Wm_s[k] = att_Wm[k];
  if (tid < 10){
    V_s[tid]  = att_V[tid];
    bq_s[tid] = att_bq[tid];
    bm_s[tid] = att_bm[tid];
    float acc = 0.f;                         // wloc = loc_Wconv @ loc_Wd (k=1 conv collapses)
    for (int cf=0; cf<CFDIM; ++cf) acc += loc_Wc[cf] * loc_Wd[cf*10 + tid];
    wloc_s[tid] = acc;
  }
  if (tid < 20){ outW_s[tid] = out_W[tid]; h_s[tid] = 0.f; c_s[tid] = 0.f; }
  if (tid < LEN) attn_s[tid] = 0.f;
  const float bv = att_bv[0];
  const float ob = out_b[0];

  // ---- per-thread fp32 weight columns (static-index unrolled) ----
  float wx[80], wh[20], dwx[20], dwh[20];
  float eb = 0.f, db = 0.f;
  if (tid < 80){
    #pragma unroll
    for (int i=0;i<80;i++) wx[i] = enc_Wx[i*80 + tid];
    #pragma unroll
    for (int u=0;u<20;u++){ wh[u] = enc_Wh[u*80 + tid]; dwx[u] = dec_Wx[u*80 + tid]; dwh[u] = dec_Wh[u*80 + tid]; }
    eb = enc_b[tid]; db = dec_b[tid];
  }
  float wq[20];
  if (tid < 10){
    #pragma unroll
    for (int u=0;u<20;u++) wq[u] = att_Wq[u*10 + tid];
  }
  __syncthreads();

  // ================= encoder =================
  for (int t=0;t<LEN;t++){
    if (tid < 80) x_s[tid] = inp[t*FDIM + tid];
    __syncthreads();
    if (tid < 80){
      float acc = eb;
      #pragma unroll
      for (int i=0;i<80;i++) acc += x_s[i] * wx[i];
      #pragma unroll
      for (int u=0;u<20;u++) acc += h_s[u] * wh[u];
      z_s[tid] = acc;
    }
    __syncthreads();
    if (tid < 20){
      float zi=z_s[tid], zf=z_s[tid+20], zg=z_s[tid+40], zo=z_s[tid+60];
      float c = sigm(zf)*c_s[tid] + sigm(zi)*ftanh(zg);
      float h = sigm(zo)*ftanh(c);
      c_s[tid] = c; h_s[tid] = h; eo[t*21 + tid] = h;
    }
    __syncthreads();
  }

  // ---- mem_proj = enc_out @ att_Wm + att_bm ----
  if (tid < LEN){
    for (int a=0;a<10;a++){
      float acc = bm_s[a];
      #pragma unroll
      for (int u=0;u<20;u++) acc += eo[tid*21 + u] * Wm_s[u*10 + a];
      mp[tid*11 + a] = acc;
    }
  }
  if (tid < 20){ h_s[tid] = 0.f; c_s[tid] = 0.f; }   // decoder state restarts at zero
  __syncthreads();

  // ================= decoder =================
  for (int t=0;t<TDEC;t++){
    // q = c @ att_Wq + bq   (query from CELL state, per reference)
    if (tid < 10){
      float acc = bq_s[tid];
      #pragma unroll
      for (int u=0;u<20;u++) acc += c_s[u] * wq[u];
      q_s[tid] = acc;
    }
    __syncthreads();

    // scores: sc[l] = sum_a tanh( mp[l][a] + q[a] + tanh(aprev[l]*wloc[a]) ) * V[a] + bv
    float sc = -INFINITY;
    if (tid < LEN){
      float ap  = attn_s[tid];
      float acc = bv;
      for (int a=0;a<10;a++){
        float pre = mp[tid*11 + a] + q_s[a] + ftanh(wloc_s[a]*ap);
        acc += ftanh(pre) * V_s[a];
      }
      sc = acc;
    }
    // softmax over l
    float mx = sc;
    #pragma unroll
    for (int off=32; off>=1; off>>=1) mx = fmaxf(mx, __shfl_xor(mx, off, 64));
    if (lane == 0) red[wid] = mx;
    __syncthreads();
    mx = fmaxf(red[0], red[1]);
    float e = (tid < LEN) ? __expf(sc - mx) : 0.f;
    float s = e;
    #pragma unroll
    for (int off=32; off>=1; off>>=1) s += __shfl_xor(s, off, 64);
    if (lane == 0) red[2+wid] = s;
    __syncthreads();
    float inv = 1.0f / (red[2] + red[3]);
    if (tid < LEN) attn_s[tid] = e * inv;
    __syncthreads();

    // ctx[u] = sum_l attn[l] * eo[l][u]  (6 groups over l)
    if (tid < 120){
      int g = tid/20, u = tid%20;
      float p = 0.f;
      for (int l=g; l<LEN; l+=6) p += attn_s[l] * eo[l*21 + u];
      pctx[tid] = p;
    }
    __syncthreads();
    if (tid < 20){
      ctx_s[tid] = ((pctx[tid] + pctx[tid+20]) + (pctx[tid+40] + pctx[tid+60]))
                 + (pctx[tid+80] + pctx[tid+100]);
    }
    __syncthreads();

    // z = ctx @ dec_Wx + h @ dec_Wh + dec_b
    if (tid < 80){
      float acc = db;
      #pragma unroll
      for (int u=0;u<20;u++) acc += ctx_s[u]*dwx[u] + h_s[u]*dwh[u];
      z_s[tid] = acc;
    }
    __syncthreads();

    // gates
    if (tid < 20){
      float zi=z_s[tid], zf=z_s[tid+20], zg=z_s[tid+40], zo=z_s[tid+60];
      float c = sigm(zf)*c_s[tid] + sigm(zi)*ftanh(zg);
      float h = sigm(zo)*ftanh(c);
      c_s[tid] = c; h_s[tid] = h;
    }
    __syncthreads();

    // y = tanh(h @ out_W + out_b)
    if (tid == 0){
      float acc = ob;
      #pragma unroll
      for (int u=0;u<20;u++) acc += h_s[u] * outW_s[u];
      g_out[(size_t)b*TDEC + t] = ftanh(acc);
    }
    __syncthreads();
  }
}

extern "C" void kernel_launch(void* const* d_in, const int* in_sizes, int n_in,
                              void* d_out, int out_size, void* d_ws, size_t ws_size,
                              hipStream_t stream) {
  const float* g_in   = (const float*)d_in[0];
  const float* enc_Wx = (const float*)d_in[1];
  const float* enc_Wh = (const float*)d_in[2];
  const float* enc_b  = (const float*)d_in[3];
  const float* att_Wq = (const float*)d_in[4];
  const float* att_bq = (const float*)d_in[5];
  const float* att_Wm = (const float*)d_in[6];
  const float* att_bm = (const float*)d_in[7];
  const float* att_V  = (const float*)d_in[8];
  const float* att_bv = (const float*)d_in[9];
  const float* loc_Wc = (const float*)d_in[10];
  const float* loc_Wd = (const float*)d_in[11];
  const float* dec_Wx = (const float*)d_in[12];
  const float* dec_Wh = (const float*)d_in[13];
  const float* dec_b  = (const float*)d_in[14];
  const float* out_W  = (const float*)d_in[15];
  const float* out_b  = (const float*)d_in[16];
  float* g_out = (float*)d_out;

  hipLaunchKernelGGL(attn_rnn_kernel, dim3(NB), dim3(128), 0, stream,
                     g_in, enc_Wx, enc_Wh, enc_b, att_Wq, att_bq, att_Wm, att_bm,
                     att_V, att_bv, loc_Wc, loc_Wd, dec_Wx, dec_Wh, dec_b,
                     out_W, out_b, g_out);
}

// Round 6
// 776.103 us; speedup vs baseline: 3.0617x; 1.0355x over previous
//
#include <hip/hip_runtime.h>
#include <math.h>

#define NB    512
#define FDIM  80
#define LEN   111
#define TDEC  222
#define CFDIM 32
#define EOS   113   // eoT row stride: coprime with 32 banks -> conflict-free

__device__ __forceinline__ float rcpf(float x){ return __builtin_amdgcn_rcpf(x); }
__device__ __forceinline__ float sigm(float x){
  return rcpf(1.0f + __expf(-x));
}
__device__ __forceinline__ float ftanh(float x){
  float ax = fabsf(x);
  float t  = __expf(-2.0f*ax);
  float r  = (1.0f - t) * rcpf(1.0f + t);
  return copysignf(r, x);
}

// One wave (64 lanes) per batch element. 512 blocks, 2 blocks/CU.
// All phase handoffs are intra-wave: __syncthreads has no cross-wave wait.
__global__ __launch_bounds__(64, 1)
void attn_rnn_kernel(const float* __restrict__ g_in,
                     const float* __restrict__ enc_Wx, const float* __restrict__ enc_Wh, const float* __restrict__ enc_b,
                     const float* __restrict__ att_Wq, const float* __restrict__ att_bq,
                     const float* __restrict__ att_Wm, const float* __restrict__ att_bm,
                     const float* __restrict__ att_V,  const float* __restrict__ att_bv,
                     const float* __restrict__ loc_Wc, const float* __restrict__ loc_Wd,
                     const float* __restrict__ dec_Wx, const float* __restrict__ dec_Wh, const float* __restrict__ dec_b,
                     const float* __restrict__ out_W,  const float* __restrict__ out_b,
                     float* __restrict__ g_out)
{
  __shared__ float xp[LEN*80];       // x @ enc_Wx + enc_b   [111][80]
  __shared__ float eoT[20*EOS];      // encoder h TRANSPOSED [u][t], stride 113
  __shared__ float mp[128*11];       // mem_proj [111][10] pad-11, rows 111..127 = scratch for dual-lane reads
  __shared__ float attn_s[LEN];      // unnormalized e within a step
  __shared__ float hc_s[40];         // interleaved: [2u]=ctx[u], [2u+1]=h[u]
  __shared__ float z_s[80];
  __shared__ float c_s[20];
  __shared__ float q_s[10];
  __shared__ float Wm_s[200];
  __shared__ float V_s[10], wloc_s[10], bm_s[10];

  const int lane = threadIdx.x;        // 0..63, one wave
  const int b    = blockIdx.x;
  const float* inp = g_in + (size_t)b * LEN * FDIM;

  // ---- stage small weights (64-lane strided: full coverage) ----
  for (int k = lane; k < 200; k += 64) Wm_s[k] = att_Wm[k];
  if (lane < 10){
    V_s[lane]  = att_V[lane];
    bm_s[lane] = att_bm[lane];
    float acc = 0.f;                    // wloc = loc_Wconv @ loc_Wd (k=1 conv collapses)
    for (int cf = 0; cf < CFDIM; ++cf) acc += loc_Wc[cf] * loc_Wd[cf*10 + lane];
    wloc_s[lane] = acc;
  }
  if (lane < 20) hc_s[2*lane+1] = 0.f;  // encoder h0 = 0
  const float bv  = att_bv[0];
  const float ob  = out_b[0];
  const float bq0 = (lane < 10) ? att_bq[lane] : 0.f;
  const float outw= (lane < 20) ? out_W[lane]  : 0.f;

  // ---- xp prologue: xp[t][j] = x[t].Wx[:,j] + b[j] ----
  // pass 1: cols 0..63 (lane j owns col j)
  {
    float wxc[80];
    #pragma unroll
    for (int i = 0; i < 80; i++) wxc[i] = enc_Wx[i*80 + lane];
    const float ebj = enc_b[lane];
    for (int t = 0; t < LEN; t++){
      const float* xr = inp + t*FDIM;
      float a0=0.f,a1=0.f,a2=0.f,a3=0.f;
      #pragma unroll
      for (int i = 0; i < 80; i += 4){
        a0 += xr[i  ]*wxc[i  ]; a1 += xr[i+1]*wxc[i+1];
        a2 += xr[i+2]*wxc[i+2]; a3 += xr[i+3]*wxc[i+3];
      }
      xp[t*80 + lane] = ebj + ((a0+a1)+(a2+a3));
    }
  }
  // pass 2: cols 64..79 (4 lanes per col, t strided by 4)
  {
    const int col = 64 + (lane >> 2);
    float wxc[80];
    #pragma unroll
    for (int i = 0; i < 80; i++) wxc[i] = enc_Wx[i*80 + col];
    const float ebj = enc_b[col];
    for (int t = (lane & 3); t < LEN; t += 4){
      const float* xr = inp + t*FDIM;
      float a0=0.f,a1=0.f,a2=0.f,a3=0.f;
      #pragma unroll
      for (int i = 0; i < 80; i += 4){
        a0 += xr[i  ]*wxc[i  ]; a1 += xr[i+1]*wxc[i+1];
        a2 += xr[i+2]*wxc[i+2]; a3 += xr[i+3]*wxc[i+3];
      }
      xp[t*80 + col] = ebj + ((a0+a1)+(a2+a3));
    }
  }

  // ---- encoder recurrent weights: col j in regs; lanes 0..15 also col 64+j ----
  const int c1 = 64 + (lane & 15);      // valid index for ALL lanes (no OOB)
  float wh0[20], wh1[20];
  #pragma unroll
  for (int u = 0; u < 20; u++){ wh0[u] = enc_Wh[u*80 + lane]; wh1[u] = enc_Wh[u*80 + c1]; }
  __syncthreads();                       // xp + h0 visible

  // ================= encoder =================
  float c_enc = 0.f;                     // lane u<20 owns c[u]
  for (int t = 0; t < LEN; t++){
    float acc0 = xp[t*80 + lane];
    float acc1 = xp[t*80 + c1];
    #pragma unroll
    for (int u = 0; u < 20; u++){
      float hu = hc_s[2*u+1];            // broadcast read
      acc0 += hu*wh0[u];
      acc1 += hu*wh1[u];
    }
    z_s[lane] = acc0;
    if (lane < 16) z_s[64 + lane] = acc1;
    __syncthreads();
    if (lane < 20){
      float zi=z_s[lane], zf=z_s[lane+20], zg=z_s[lane+40], zo=z_s[lane+60];
      c_enc = sigm(zf)*c_enc + sigm(zi)*ftanh(zg);
      float h = sigm(zo)*ftanh(c_enc);
      hc_s[2*lane+1] = h;
      eoT[lane*EOS + t] = h;             // transposed store
    }
    __syncthreads();
  }

  // ---- decoder weights (loaded after encoder to cap register peak) ----
  float dwx0[20], dwx1[20], dwh0[20], dwh1[20];
  #pragma unroll
  for (int u = 0; u < 20; u++){
    dwx0[u] = dec_Wx[u*80 + lane]; dwx1[u] = dec_Wx[u*80 + c1];
    dwh0[u] = dec_Wh[u*80 + lane]; dwh1[u] = dec_Wh[u*80 + c1];
  }
  const float db0 = dec_b[lane];
  const float db1 = dec_b[c1];
  float wq[20];
  if (lane < 10){
    #pragma unroll
    for (int u = 0; u < 20; u++) wq[u] = att_Wq[u*10 + lane];
  }

  // ---- mem_proj = enc_out @ att_Wm + att_bm  (dual-l per lane) ----
  #pragma unroll
  for (int rep = 0; rep < 2; rep++){
    int l = lane + rep*64;
    if (l < LEN){
      float er[20];
      #pragma unroll
      for (int u = 0; u < 20; u++) er[u] = eoT[u*EOS + l];
      #pragma unroll
      for (int a = 0; a < 10; a++){
        float m0 = bm_s[a];
        #pragma unroll
        for (int u = 0; u < 20; u++) m0 += er[u]*Wm_s[u*10 + a];
        mp[l*11 + a] = m0;
      }
    }
  }
  if (lane < 20){ hc_s[2*lane+1] = 0.f; c_s[lane] = 0.f; }  // decoder state = 0
  __syncthreads();

  // ================= decoder =================
  float ap0 = 0.f, ap1 = 0.f;           // prev attention, lane-resident
  float c_dec = 0.f;
  for (int t = 0; t < TDEC; t++){
    // q = c @ att_Wq + bq  (query from CELL state, per reference)
    if (lane < 10){
      float acc = bq0;
      #pragma unroll
      for (int u = 0; u < 20; u++) acc += c_s[u]*wq[u];
      q_s[lane] = acc;
    }
    __syncthreads();

    // scores (dual-l): sc[l] = bv + sum_a tanh(mp[l][a] + q[a] + tanh(ap[l]*wloc[a]))*V[a]
    float qr[10];
    #pragma unroll
    for (int a = 0; a < 10; a++) qr[a] = q_s[a];
    float acc0 = bv, acc1 = bv;
    #pragma unroll
    for (int a = 0; a < 10; a++){
      float pre0 = mp[lane*11 + a]      + qr[a] + ftanh(wloc_s[a]*ap0);
      float pre1 = mp[(lane+64)*11 + a] + qr[a] + ftanh(wloc_s[a]*ap1); // rows >=111 = scratch, masked below
      acc0 += ftanh(pre0)*V_s[a];
      acc1 += ftanh(pre1)*V_s[a];
    }
    // |sc| <= |bv| + sum|V| (~3): exp cannot overflow -> skip max subtraction
    float e0 = __expf(acc0);
    float e1 = (lane < 47) ? __expf(acc1) : 0.f;
    attn_s[lane] = e0;
    if (lane < 47) attn_s[lane + 64] = e1;
    float s = e0 + e1;
    #pragma unroll
    for (int off = 32; off; off >>= 1) s += __shfl_xor(s, off, 64);
    float inv = rcpf(s);
    ap0 = e0*inv; ap1 = e1*inv;          // normalized attn for next step's loc term
    __syncthreads();                     // e visible for ctx

    // ctx[u] = inv * sum_l e[l]*eo[l][u]; lanes (g*20+u), g<3, contiguous 37-l runs
    float part = 0.f;
    {
      int u = lane % 20, g = lane / 20;
      if (lane < 60){
        int l0 = g*37;
        const float* eor = &eoT[u*EOS + l0];
        const float* ar  = &attn_s[l0];
        #pragma unroll 4
        for (int k = 0; k < 37; k++) part += ar[k]*eor[k];
      }
    }
    float p1 = __shfl(part, lane + 20, 64);
    float p2 = __shfl(part, lane + 40, 64);
    if (lane < 20) hc_s[2*lane] = (part + p1 + p2)*inv;
    __syncthreads();                     // ctx visible

    // z = ctx @ dec_Wx + h @ dec_Wh + dec_b   (lane j -> z[j]; lanes<16 also z[64+j])
    {
      float a0 = db0, a1 = db1;
      #pragma unroll
      for (int u = 0; u < 20; u++){
        float cu = hc_s[2*u];            // broadcast
        float hu = hc_s[2*u+1];
        a0 += cu*dwx0[u] + hu*dwh0[u];
        a1 += cu*dwx1[u] + hu*dwh1[u];
      }
      z_s[lane] = a0;
      if (lane < 16) z_s[64 + lane] = a1;
    }
    __syncthreads();

    // gates + fused output reduce
    float hval = 0.f;
    if (lane < 20){
      float zi=z_s[lane], zf=z_s[lane+20], zg=z_s[lane+40], zo=z_s[lane+60];
      c_dec = sigm(zf)*c_dec + sigm(zi)*ftanh(zg);
      hval  = sigm(zo)*ftanh(c_dec);
      hc_s[2*lane+1] = hval;
      c_s[lane] = c_dec;
    }
    float pv = hval*outw;
    #pragma unroll
    for (int off = 32; off; off >>= 1) pv += __shfl_xor(pv, off, 64);
    if (lane == 0) g_out[(size_t)b*TDEC + t] = ftanh(pv + ob);
    __syncthreads();                     // h_s/c_s visible for next step
  }
}

extern "C" void kernel_launch(void* const* d_in, const int* in_sizes, int n_in,
                              void* d_out, int out_size, void* d_ws, size_t ws_size,
                              hipStream_t stream) {
  const float* g_in   = (const float*)d_in[0];
  const float* enc_Wx = (const float*)d_in[1];
  const float* enc_Wh = (const float*)d_in[2];
  const float* enc_b  = (const float*)d_in[3];
  const float* att_Wq = (const float*)d_in[4];
  const float* att_bq = (const float*)d_in[5];
  const float* att_Wm = (const float*)d_in[6];
  const float* att_bm = (const float*)d_in[7];
  const float* att_V  = (const float*)d_in[8];
  const float* att_bv = (const float*)d_in[9];
  const float* loc_Wc = (const float*)d_in[10];
  const float* loc_Wd = (const float*)d_in[11];
  const float* dec_Wx = (const float*)d_in[12];
  const float* dec_Wh = (const float*)d_in[13];
  const float* dec_b  = (const float*)d_in[14];
  const float* out_W  = (const float*)d_in[15];
  const float* out_b  = (const float*)d_in[16];
  float* g_out = (float*)d_out;

  hipLaunchKernelGGL(attn_rnn_kernel, dim3(NB), dim3(64), 0, stream,
                     g_in, enc_Wx, enc_Wh, enc_b, att_Wq, att_bq, att_Wm, att_bm,
                     att_V, att_bv, loc_Wc, loc_Wd, dec_Wx, dec_Wh, dec_b,
                     out_W, out_b, g_out);
}

// Round 8
// 699.280 us; speedup vs baseline: 3.3980x; 1.1099x over previous
//
#include <hip/hip_runtime.h>
#include <math.h>

#define NB    512
#define FDIM  80
#define LEN   111
#define TDEC  222
#define CFDIM 32
#define EOS   113   // eoT row stride: coprime with 32 banks -> conflict-free

__device__ __forceinline__ float rcpf(float x){ return __builtin_amdgcn_rcpf(x); }
__device__ __forceinline__ float sigm(float x){ return rcpf(1.0f + __expf(-x)); }
__device__ __forceinline__ float ftanh(float x){
  float ax = fabsf(x);
  float t  = __expf(-2.0f*ax);
  float r  = (1.0f - t) * rcpf(1.0f + t);
  return copysignf(r, x);
}

// DPP-based full-wave sum: 6 VALU ops, no LDS. ctrl/mask must be ICE -> template.
template<int CTRL, int ROW_MASK>
__device__ __forceinline__ float dpp_add(float x){
  int yi = __builtin_amdgcn_update_dpp(0, __builtin_bit_cast(int, x), CTRL, ROW_MASK, 0xf, false);
  return x + __builtin_bit_cast(float, yi);
}
__device__ __forceinline__ float wave_sum(float x){
  x = dpp_add<0x111, 0xf>(x);  // row_shr:1
  x = dpp_add<0x112, 0xf>(x);  // row_shr:2
  x = dpp_add<0x114, 0xf>(x);  // row_shr:4
  x = dpp_add<0x118, 0xf>(x);  // row_shr:8
  x = dpp_add<0x142, 0xa>(x);  // row_bcast:15 -> rows 1,3
  x = dpp_add<0x143, 0xc>(x);  // row_bcast:31 -> row 3
  return __builtin_bit_cast(float, __builtin_amdgcn_readlane(__builtin_bit_cast(int, x), 63));
}
#define RL(x, u) __builtin_bit_cast(float, __builtin_amdgcn_readlane(__builtin_bit_cast(int, (x)), (u)))

// One wave per batch element; 512 blocks. Occupancy is structurally capped at
// 1 wave/SIMD, so the ONLY metric that matters is serial chain length/step.
__global__ __launch_bounds__(64, 1)
void attn_rnn_kernel(const float* __restrict__ g_in,
                     const float* __restrict__ enc_Wx, const float* __restrict__ enc_Wh, const float* __restrict__ enc_b,
                     const float* __restrict__ att_Wq, const float* __restrict__ att_bq,
                     const float* __restrict__ att_Wm, const float* __restrict__ att_bm,
                     const float* __restrict__ att_V,  const float* __restrict__ att_bv,
                     const float* __restrict__ loc_Wc, const float* __restrict__ loc_Wd,
                     const float* __restrict__ dec_Wx, const float* __restrict__ dec_Wh, const float* __restrict__ dec_b,
                     const float* __restrict__ out_W,  const float* __restrict__ out_b,
                     float* __restrict__ g_out)
{
  __shared__ float xp[LEN*80];       // x @ enc_Wx + enc_b
  __shared__ float eoT[20*EOS];      // encoder h transposed [u][t]
  __shared__ float attn_s[128];      // unnormalized e
  __shared__ float z_s[80];          // gate pre-activations handoff
  __shared__ float Wm_s[200];

  const int lane = threadIdx.x;
  const int b    = blockIdx.x;
  const float* inp = g_in + (size_t)b * LEN * FDIM;

  for (int k = lane; k < 200; k += 64) Wm_s[k] = att_Wm[k];

  // ---- uniform small weights (wave-uniform addresses -> scalar loads) ----
  float V[10], wloc[10], bmv[10];
  #pragma unroll
  for (int a = 0; a < 10; a++){ V[a] = att_V[a]; bmv[a] = att_bm[a]; wloc[a] = 0.f; }
  for (int cf = 0; cf < CFDIM; ++cf){
    float lwc = loc_Wc[cf];
    #pragma unroll
    for (int a = 0; a < 10; a++) wloc[a] += lwc * loc_Wd[cf*10 + a];
  }
  const float bv = att_bv[0];
  const float ob = out_b[0];
  const float bq_l = att_bq[(lane < 10) ? lane : 0];
  const float outw = (lane < 20) ? out_W[lane] : 0.f;

  // ---- xp prologue ----
  {
    float wxc[80];
    #pragma unroll
    for (int i = 0; i < 80; i++) wxc[i] = enc_Wx[i*80 + lane];
    const float ebj = enc_b[lane];
    for (int t = 0; t < LEN; t++){
      const float* xr = inp + t*FDIM;      // uniform row -> scalar loads
      float a0=0.f,a1=0.f,a2=0.f,a3=0.f;
      #pragma unroll
      for (int i = 0; i < 80; i += 4){
        a0 += xr[i  ]*wxc[i  ]; a1 += xr[i+1]*wxc[i+1];
        a2 += xr[i+2]*wxc[i+2]; a3 += xr[i+3]*wxc[i+3];
      }
      xp[t*80 + lane] = ebj + ((a0+a1)+(a2+a3));
    }
  }
  {
    const int col = 64 + (lane >> 2);
    float wxc[80];
    #pragma unroll
    for (int i = 0; i < 80; i++) wxc[i] = enc_Wx[i*80 + col];
    const float ebj = enc_b[col];
    for (int t = (lane & 3); t < LEN; t += 4){
      const float* xr = inp + t*FDIM;
      float a0=0.f,a1=0.f,a2=0.f,a3=0.f;
      #pragma unroll
      for (int i = 0; i < 80; i += 4){
        a0 += xr[i  ]*wxc[i  ]; a1 += xr[i+1]*wxc[i+1];
        a2 += xr[i+2]*wxc[i+2]; a3 += xr[i+3]*wxc[i+3];
      }
      xp[t*80 + col] = ebj + ((a0+a1)+(a2+a3));
    }
  }

  const int c1 = 64 + (lane & 15);
  float wh0[20], wh1[20];
  #pragma unroll
  for (int u = 0; u < 20; u++){ wh0[u] = enc_Wh[u*80 + lane]; wh1[u] = enc_Wh[u*80 + c1]; }
  __syncthreads();                         // xp + Wm_s visible

  // ================= encoder (h broadcast held in s_h) =================
  float s_h[20];
  #pragma unroll
  for (int u = 0; u < 20; u++) s_h[u] = 0.f;
  float c_enc = 0.f;
  for (int t = 0; t < LEN; t++){
    float acc0 = xp[t*80 + lane];
    float acc1 = xp[t*80 + c1];
    #pragma unroll
    for (int u = 0; u < 20; u++){ acc0 += s_h[u]*wh0[u]; acc1 += s_h[u]*wh1[u]; }
    z_s[lane] = acc0;
    if (lane < 16) z_s[64 + lane] = acc1;
    __syncthreads();
    float hval = 0.f;
    if (lane < 20){
      float zi=z_s[lane], zf=z_s[lane+20], zg=z_s[lane+40], zo=z_s[lane+60];
      c_enc = sigm(zf)*c_enc + sigm(zi)*ftanh(zg);
      hval  = sigm(zo)*ftanh(c_enc);
      eoT[lane*EOS + t] = hval;
    }
    #pragma unroll
    for (int u = 0; u < 20; u++) s_h[u] = RL(hval, u);
    __syncthreads();                       // protect z_s WAR for next t
  }

  // ---- mem_proj rows -> REGISTERS (no LDS in the scores phase) ----
  float mp0[10], mp1[10];
  {
    const int l1 = (lane < 47) ? lane + 64 : lane;
    float er0[20], er1[20];
    #pragma unroll
    for (int u = 0; u < 20; u++){ er0[u] = eoT[u*EOS + lane]; er1[u] = eoT[u*EOS + l1]; }
    #pragma unroll
    for (int a = 0; a < 10; a++){
      float m0 = bmv[a], m1 = bmv[a];
      #pragma unroll
      for (int u = 0; u < 20; u++){ m0 += er0[u]*Wm_s[u*10 + a]; m1 += er1[u]*Wm_s[u*10 + a]; }
      mp0[a] = m0; mp1[a] = m1;
    }
  }

  // ---- decoder weights ----
  float dwx0[20], dwx1[20], dwh0[20], dwh1[20];
  #pragma unroll
  for (int u = 0; u < 20; u++){
    dwx0[u] = dec_Wx[u*80 + lane]; dwx1[u] = dec_Wx[u*80 + c1];
    dwh0[u] = dec_Wh[u*80 + lane]; dwh1[u] = dec_Wh[u*80 + c1];
  }
  const float db0 = dec_b[lane];
  const float db1 = dec_b[c1];
  float wq[20];
  if (lane < 10){
    #pragma unroll
    for (int u = 0; u < 20; u++) wq[u] = att_Wq[u*10 + lane];
  }

  // ctx assignment (loop-invariant)
  const int u20 = lane % 20;
  const int grp = lane / 20;
  const float* eor = &eoT[u20*EOS + grp*37];
  const float* arr = &attn_s[grp*37];

  float s_c[20];
  #pragma unroll
  for (int u = 0; u < 20; u++){ s_c[u] = 0.f; s_h[u] = 0.f; }

  // ================= decoder =================
  float ap0 = 0.f, ap1 = 0.f, c_dec = 0.f;
  for (int t = 0; t < TDEC; t++){
    // q = c @ att_Wq + bq (query from CELL state, per reference); lanes 0..9
    float qv = bq_l;
    if (lane < 10){
      #pragma unroll
      for (int u = 0; u < 20; u++) qv += s_c[u]*wq[u];
    }
    float s_q[10];
    #pragma unroll
    for (int a = 0; a < 10; a++) s_q[a] = RL(qv, a);

    // scores: register-only (mp in regs, q/wloc/V uniform)
    float acc0 = bv, acc1 = bv;
    #pragma unroll
    for (int a = 0; a < 10; a++){
      float pre0 = mp0[a] + s_q[a] + ftanh(wloc[a]*ap0);
      float pre1 = mp1[a] + s_q[a] + ftanh(wloc[a]*ap1);
      acc0 += ftanh(pre0)*V[a];
      acc1 += ftanh(pre1)*V[a];
    }
    // |sc| <= |bv|+sum|V| (~3): exp cannot overflow -> no max subtraction
    float e0 = __expf(acc0);
    float e1 = (lane < 47) ? __expf(acc1) : 0.f;
    attn_s[lane]      = e0;
    attn_s[64 + lane] = e1;                    // lanes>=47 write 0 to 111..127 (pad)
    float inv = rcpf(wave_sum(e0 + e1));       // DPP reduce overlaps the LDS writes
    ap0 = e0*inv; ap1 = e1*inv;
    __syncthreads();                           // attn_s visible

    // ctx partials: 60 lanes x 37 l's, then 2 shfl + per-lane combine
    float part = 0.f;
    if (lane < 60){
      #pragma unroll 4
      for (int k = 0; k < 37; k++) part += arr[k]*eor[k];
    }
    float p1 = __shfl(part, lane + 20, 64);
    float p2 = __shfl(part, lane + 40, 64);
    float ctxv = (part + p1 + p2)*inv;
    float s_ctx[20];
    #pragma unroll
    for (int u = 0; u < 20; u++) s_ctx[u] = RL(ctxv, u);

    // z = ctx @ dec_Wx + h @ dec_Wh + dec_b  (broadcast scalars x VGPR weights)
    float a0 = db0, a1 = db1;
    #pragma unroll
    for (int u = 0; u < 20; u++){
      a0 += s_ctx[u]*dwx0[u] + s_h[u]*dwh0[u];
      a1 += s_ctx[u]*dwx1[u] + s_h[u]*dwh1[u];
    }
    z_s[lane] = a0;
    if (lane < 16) z_s[64 + lane] = a1;
    __syncthreads();

    // gates (lanes 0..19)
    float hval = 0.f;
    if (lane < 20){
      float zi=z_s[lane], zf=z_s[lane+20], zg=z_s[lane+40], zo=z_s[lane+60];
      c_dec = sigm(zf)*c_dec + sigm(zi)*ftanh(zg);
      hval  = sigm(zo)*ftanh(c_dec);
    }

    // y = tanh(h.out_W + ob): DPP reduce, uniform result
    float pv = wave_sum(hval*outw);
    if (lane == 0) g_out[(size_t)b*TDEC + t] = ftanh(pv + ob);

    // broadcast new state for next step
    #pragma unroll
    for (int u = 0; u < 20; u++){ s_c[u] = RL(c_dec, u); s_h[u] = RL(hval, u); }
    __syncthreads();                           // protect z_s/attn_s WAR
  }
}

extern "C" void kernel_launch(void* const* d_in, const int* in_sizes, int n_in,
                              void* d_out, int out_size, void* d_ws, size_t ws_size,
                              hipStream_t stream) {
  const float* g_in   = (const float*)d_in[0];
  const float* enc_Wx = (const float*)d_in[1];
  const float* enc_Wh = (const float*)d_in[2];
  const float* enc_b  = (const float*)d_in[3];
  const float* att_Wq = (const float*)d_in[4];
  const float* att_bq = (const float*)d_in[5];
  const float* att_Wm = (const float*)d_in[6];
  const float* att_bm = (const float*)d_in[7];
  const float* att_V  = (const float*)d_in[8];
  const float* att_bv = (const float*)d_in[9];
  const float* loc_Wc = (const float*)d_in[10];
  const float* loc_Wd = (const float*)d_in[11];
  const float* dec_Wx = (const float*)d_in[12];
  const float* dec_Wh = (const float*)d_in[13];
  const float* dec_b  = (const float*)d_in[14];
  const float* out_W  = (const float*)d_in[15];
  const float* out_b  = (const float*)d_in[16];
  float* g_out = (float*)d_out;

  hipLaunchKernelGGL(attn_rnn_kernel, dim3(NB), dim3(64), 0, stream,
                     g_in, enc_Wx, enc_Wh, enc_b, att_Wq, att_bq, att_Wm, att_bm,
                     att_V, att_bv, loc_Wc, loc_Wd, dec_Wx, dec_Wh, dec_b,
                     out_W, out_b, g_out);
}

// Round 9
// 555.685 us; speedup vs baseline: 4.2761x; 1.2584x over previous
//
#include <hip/hip_runtime.h>
#include <math.h>

#define NB    512
#define FDIM  80
#define LEN   111
#define TDEC  222
#define CFDIM 32
#define EOS   113   // eoT row stride: coprime with 32 banks -> conflict-free

__device__ __forceinline__ float rcpf(float x){ return __builtin_amdgcn_rcpf(x); }
__device__ __forceinline__ float sigm(float x){ return rcpf(1.0f + __expf(-x)); }
// tanh(x) = 1 - 2/(e^{2x}+1): 5 ops, valid for |x| < 40 (our args are < ~6)
__device__ __forceinline__ float ftanh(float x){
  float e = __expf(2.0f*x);
  return 1.0f - 2.0f*rcpf(e + 1.0f);
}

// DPP-based full-wave sum: 6 VALU ops + readlane; result wave-uniform.
template<int CTRL, int ROW_MASK>
__device__ __forceinline__ float dpp_add(float x){
  int yi = __builtin_amdgcn_update_dpp(0, __builtin_bit_cast(int, x), CTRL, ROW_MASK, 0xf, false);
  return x + __builtin_bit_cast(float, yi);
}
__device__ __forceinline__ float wave_sum(float x){
  x = dpp_add<0x111, 0xf>(x);  // row_shr:1
  x = dpp_add<0x112, 0xf>(x);  // row_shr:2
  x = dpp_add<0x114, 0xf>(x);  // row_shr:4
  x = dpp_add<0x118, 0xf>(x);  // row_shr:8
  x = dpp_add<0x142, 0xa>(x);  // row_bcast:15
  x = dpp_add<0x143, 0xc>(x);  // row_bcast:31
  return __builtin_bit_cast(float, __builtin_amdgcn_readlane(__builtin_bit_cast(int, x), 63));
}
#define RL(x, u) __builtin_bit_cast(float, __builtin_amdgcn_readlane(__builtin_bit_cast(int, (x)), (u)))
#define BPERM(src, idx) __builtin_bit_cast(float, __builtin_amdgcn_ds_bpermute(((idx)&63)*4, __builtin_bit_cast(int, (src))))

// One wave per batch element; 512 blocks; occupancy structurally capped, so the
// only metric that matters is the serial dependence chain per recurrence step.
// Design rule: NO LDS memory round-trips, NO barriers inside the t-loops.
__global__ __launch_bounds__(64, 1)
void attn_rnn_kernel(const float* __restrict__ g_in,
                     const float* __restrict__ enc_Wx, const float* __restrict__ enc_Wh, const float* __restrict__ enc_b,
                     const float* __restrict__ att_Wq, const float* __restrict__ att_bq,
                     const float* __restrict__ att_Wm, const float* __restrict__ att_bm,
                     const float* __restrict__ att_V,  const float* __restrict__ att_bv,
                     const float* __restrict__ loc_Wc, const float* __restrict__ loc_Wd,
                     const float* __restrict__ dec_Wx, const float* __restrict__ dec_Wh, const float* __restrict__ dec_b,
                     const float* __restrict__ out_W,  const float* __restrict__ out_b,
                     float* __restrict__ g_out)
{
  __shared__ float xp[LEN*80];       // x @ enc_Wx + enc_b (read-only after prologue)
  __shared__ float eoT[20*EOS];      // encoder h transposed [u][t] (read-only after encoder)
  __shared__ float Wm_s[200];

  const int lane = threadIdx.x;
  const int b    = blockIdx.x;
  const float* inp = g_in + (size_t)b * LEN * FDIM;

  for (int k = lane; k < 200; k += 64) Wm_s[k] = att_Wm[k];

  // ---- uniform small weights (wave-uniform addresses -> scalar loads) ----
  float V[10], wloc[10], bmv[10];
  #pragma unroll
  for (int a = 0; a < 10; a++){ V[a] = att_V[a]; bmv[a] = att_bm[a]; wloc[a] = 0.f; }
  for (int cf = 0; cf < CFDIM; ++cf){
    float lwc = loc_Wc[cf];
    #pragma unroll
    for (int a = 0; a < 10; a++) wloc[a] += lwc * loc_Wd[cf*10 + a];
  }
  const float bv = att_bv[0];
  const float ob = out_b[0];
  const float bq_l = att_bq[(lane < 10) ? lane : 0];
  const float outw = (lane < 20) ? out_W[lane] : 0.f;

  // ---- xp prologue: xp[t][j] = x[t].Wx[:,j] + b[j] ----
  {
    float wxc[80];
    #pragma unroll
    for (int i = 0; i < 80; i++) wxc[i] = enc_Wx[i*80 + lane];
    const float ebj = enc_b[lane];
    for (int t = 0; t < LEN; t++){
      const float* xr = inp + t*FDIM;
      float a0=0.f,a1=0.f,a2=0.f,a3=0.f;
      #pragma unroll
      for (int i = 0; i < 80; i += 4){
        a0 += xr[i  ]*wxc[i  ]; a1 += xr[i+1]*wxc[i+1];
        a2 += xr[i+2]*wxc[i+2]; a3 += xr[i+3]*wxc[i+3];
      }
      xp[t*80 + lane] = ebj + ((a0+a1)+(a2+a3));
    }
  }
  {
    const int col = 64 + (lane >> 2);
    float wxc[80];
    #pragma unroll
    for (int i = 0; i < 80; i++) wxc[i] = enc_Wx[i*80 + col];
    const float ebj = enc_b[col];
    for (int t = (lane & 3); t < LEN; t += 4){
      const float* xr = inp + t*FDIM;
      float a0=0.f,a1=0.f,a2=0.f,a3=0.f;
      #pragma unroll
      for (int i = 0; i < 80; i += 4){
        a0 += xr[i  ]*wxc[i  ]; a1 += xr[i+1]*wxc[i+1];
        a2 += xr[i+2]*wxc[i+2]; a3 += xr[i+3]*wxc[i+3];
      }
      xp[t*80 + col] = ebj + ((a0+a1)+(a2+a3));
    }
  }

  const int c1 = 64 + (lane & 15);
  float wh0[20], wh1[20];
  #pragma unroll
  for (int u = 0; u < 20; u++){ wh0[u] = enc_Wh[u*80 + lane]; wh1[u] = enc_Wh[u*80 + c1]; }
  __syncthreads();                         // [barrier 1/2] xp + Wm_s ready

  // ================= encoder: barrier-free =================
  float s_h[20];
  #pragma unroll
  for (int u = 0; u < 20; u++) s_h[u] = 0.f;
  float c_enc = 0.f;
  for (int t = 0; t < LEN; t++){
    float p0 = xp[t*80 + lane], q0 = 0.f;
    float p1 = xp[t*80 + c1],   q1 = 0.f;
    #pragma unroll
    for (int u = 0; u < 20; u += 2){
      p0 += s_h[u]*wh0[u];  q0 += s_h[u+1]*wh0[u+1];
      p1 += s_h[u]*wh1[u];  q1 += s_h[u+1]*wh1[u+1];
    }
    float a0 = p0 + q0, a1 = p1 + q1;      // z[lane], z[64+(lane&15)]
    // z handoff: register permute, no barrier
    float zf = BPERM(a0, lane+20);
    float zg = BPERM(a0, lane+40);
    float zoA= BPERM(a0, lane+60);
    float zoB= BPERM(a1, lane-4);
    float hval = 0.f;
    if (lane < 20){
      float zo = (lane < 4) ? zoA : zoB;
      c_enc = sigm(zf)*c_enc + sigm(a0)*ftanh(zg);
      hval  = sigm(zo)*ftanh(c_enc);
      eoT[lane*EOS + t] = hval;
    }
    #pragma unroll
    for (int u = 0; u < 20; u++) s_h[u] = RL(hval, u);
  }
  __syncthreads();                         // [barrier 2/2] eoT ready

  // ---- per-lane eo rows -> registers (LIVE through the decoder) ----
  const int l1 = (lane < 47) ? lane + 64 : lane;
  float er0[20], er1[20];
  #pragma unroll
  for (int u = 0; u < 20; u++){ er0[u] = eoT[u*EOS + lane]; er1[u] = eoT[u*EOS + l1]; }

  // ---- mem_proj rows -> registers ----
  float mp0[10], mp1[10];
  #pragma unroll
  for (int a = 0; a < 10; a++){
    float m0 = bmv[a], m1 = bmv[a];
    #pragma unroll
    for (int u = 0; u < 20; u++){ m0 += er0[u]*Wm_s[u*10 + a]; m1 += er1[u]*Wm_s[u*10 + a]; }
    mp0[a] = m0; mp1[a] = m1;
  }

  // ---- decoder weights ----
  float dwx0[20], dwx1[20], dwh0[20], dwh1[20];
  #pragma unroll
  for (int u = 0; u < 20; u++){
    dwx0[u] = dec_Wx[u*80 + lane]; dwx1[u] = dec_Wx[u*80 + c1];
    dwh0[u] = dec_Wh[u*80 + lane]; dwh1[u] = dec_Wh[u*80 + c1];
  }
  const float db0 = dec_b[lane];
  const float db1 = dec_b[c1];
  float wq[20];
  if (lane < 10){
    #pragma unroll
    for (int u = 0; u < 20; u++) wq[u] = att_Wq[u*10 + lane];
  }

  float s_c[20];
  #pragma unroll
  for (int u = 0; u < 20; u++){ s_c[u] = 0.f; s_h[u] = 0.f; }

  // ================= decoder: barrier-free, zero LDS memory =================
  float ap0 = 0.f, ap1 = 0.f, c_dec = 0.f;
  for (int t = 0; t < TDEC; t++){
    // q = c @ att_Wq + bq (query from CELL state, per reference); lanes 0..9
    float qv = bq_l;
    if (lane < 10){
      float qa = 0.f, qb = 0.f;
      #pragma unroll
      for (int u = 0; u < 20; u += 2){ qa += s_c[u]*wq[u]; qb += s_c[u+1]*wq[u+1]; }
      qv += qa + qb;
    }
    float s_q[10];
    #pragma unroll
    for (int a = 0; a < 10; a++) s_q[a] = RL(qv, a);

    // scores: pure registers
    float sa0 = bv, sb0 = 0.f, sa1 = bv, sb1 = 0.f;
    #pragma unroll
    for (int a = 0; a < 10; a += 2){
      float pre0 = mp0[a]   + s_q[a]   + ftanh(wloc[a]*ap0);
      float pre1 = mp1[a]   + s_q[a]   + ftanh(wloc[a]*ap1);
      float pr20 = mp0[a+1] + s_q[a+1] + ftanh(wloc[a+1]*ap0);
      float pr21 = mp1[a+1] + s_q[a+1] + ftanh(wloc[a+1]*ap1);
      sa0 += ftanh(pre0)*V[a];   sa1 += ftanh(pre1)*V[a];
      sb0 += ftanh(pr20)*V[a+1]; sb1 += ftanh(pr21)*V[a+1];
    }
    // |sc| <= |bv|+sum|V| (~2): exp cannot overflow -> no max subtraction
    float e0 = __expf(sa0 + sb0);
    float e1 = (lane < 47) ? __expf(sa1 + sb1) : 0.f;
    float inv = rcpf(wave_sum(e0 + e1));
    ap0 = e0*inv; ap1 = e1*inv;

    // ctx[u] = inv * sum_l e[l]*eo[l][u] : lane-local FMAs + 20 DPP trees
    float s_ctx[20];
    #pragma unroll
    for (int u = 0; u < 20; u++){
      s_ctx[u] = wave_sum(e0*er0[u] + e1*er1[u]) * inv;
    }

    // z = ctx @ dec_Wx + h @ dec_Wh + dec_b (split accumulators)
    float x0 = db0, h0 = 0.f, x1 = db1, h1 = 0.f;
    #pragma unroll
    for (int u = 0; u < 20; u++){
      x0 += s_ctx[u]*dwx0[u]; h0 += s_h[u]*dwh0[u];
      x1 += s_ctx[u]*dwx1[u]; h1 += s_h[u]*dwh1[u];
    }
    float a0 = x0 + h0, a1 = x1 + h1;
    // z handoff: register permute, no barrier
    float zf = BPERM(a0, lane+20);
    float zg = BPERM(a0, lane+40);
    float zoA= BPERM(a0, lane+60);
    float zoB= BPERM(a1, lane-4);

    float hval = 0.f;
    if (lane < 20){
      float zo = (lane < 4) ? zoA : zoB;
      c_dec = sigm(zf)*c_dec + sigm(a0)*ftanh(zg);
      hval  = sigm(zo)*ftanh(c_dec);
    }

    // y = tanh(h.out_W + ob)
    float pv = wave_sum(hval*outw);
    if (lane == 0) g_out[(size_t)b*TDEC + t] = ftanh(pv + ob);

    // state broadcast for next step
    #pragma unroll
    for (int u = 0; u < 20; u++){ s_c[u] = RL(c_dec, u); s_h[u] = RL(hval, u); }
  }
}

extern "C" void kernel_launch(void* const* d_in, const int* in_sizes, int n_in,
                              void* d_out, int out_size, void* d_ws, size_t ws_size,
                              hipStream_t stream) {
  const float* g_in   = (const float*)d_in[0];
  const float* enc_Wx = (const float*)d_in[1];
  const float* enc_Wh = (const float*)d_in[2];
  const float* enc_b  = (const float*)d_in[3];
  const float* att_Wq = (const float*)d_in[4];
  const float* att_bq = (const float*)d_in[5];
  const float* att_Wm = (const float*)d_in[6];
  const float* att_bm = (const float*)d_in[7];
  const float* att_V  = (const float*)d_in[8];
  const float* att_bv = (const float*)d_in[9];
  const float* loc_Wc = (const float*)d_in[10];
  const float* loc_Wd = (const float*)d_in[11];
  const float* dec_Wx = (const float*)d_in[12];
  const float* dec_Wh = (const float*)d_in[13];
  const float* dec_b  = (const float*)d_in[14];
  const float* out_W  = (const float*)d_in[15];
  const float* out_b  = (const float*)d_in[16];
  float* g_out = (float*)d_out;

  hipLaunchKernelGGL(attn_rnn_kernel, dim3(NB), dim3(64), 0, stream,
                     g_in, enc_Wx, enc_Wh, enc_b, att_Wq, att_bq, att_Wm, att_bm,
                     att_V, att_bv, loc_Wc, loc_Wd, dec_Wx, dec_Wh, dec_b,
                     out_W, out_b, g_out);
}